// Round 19
// baseline (42.248 us; speedup 1.0000x reference)
//
#include <hip/hip_runtime.h>

typedef float f4 __attribute__((ext_vector_type(4)));
typedef float f2 __attribute__((ext_vector_type(2)));
typedef float f32x4 __attribute__((ext_vector_type(4)));
typedef __bf16 bf16x8 __attribute__((ext_vector_type(8)));
typedef __bf16 bf16x4 __attribute__((ext_vector_type(4)));
typedef __bf16 bf16x2 __attribute__((ext_vector_type(2)));

#define NPSIDE 24

// Block = (b, head, 1x4 patch strip), 256 threads = 4 waves, wave = 1 patch.
// XCD-aligned mapping (R17): XCD k owns bs in [36k, 36k+36) for all 8 heads.
// Staging transforms x -> K/Q/V bf16 ONCE per region into MFMA-ready LDS:
//   Kreg[region_px 160][ch 32 +8]   (region px = row*20+col)
//   Qreg[patch 4][own_px 16][ch 32 +8]
//   Vreg[ch 32][row*24+col, 196]    (8 contiguous px per b64-pair read)
// Math phase: pure vector LDS reads + MFMA + softmax (no per-patch transform).
__global__ __launch_bounds__(256, 4) void patch_attn(
    const float* __restrict__ x,
    const float* __restrict__ qkv_w,
    const float* __restrict__ qkv_b,
    const float* __restrict__ pos_table,
    const float* __restrict__ wmat,
    __bf16* __restrict__ mid,
    __bf16* __restrict__ wbf)
{
    __shared__ __bf16 Kreg[160][40];      // 12.8 KB
    __shared__ __bf16 Qreg[4][16][40];    // 5.1 KB
    __shared__ __bf16 Vreg[32][196];      // 12.5 KB
    __shared__ __bf16 Ps[4][16][72];      // 9.2 KB   total 38.8 KB

    const int t = threadIdx.x;

    // side job: out_w fp32 -> bf16 fragment-linear (blocks 0..63, raw id)
    if (blockIdx.x < 64) {
        const int i = (blockIdx.x * 256 + t) * 4;   // o*256+c
        const int o = i >> 8, c = i & 255;
        const f4 v = *(const f4*)&wmat[i];
        bf16x4 ov;
        #pragma unroll
        for (int j = 0; j < 4; ++j) ov[j] = (__bf16)v[j];
        *(bf16x4*)&wbf[((o >> 4) * 8 + (c >> 5)) * 512 + (o & 15) * 32 + (c & 31)] = ov;
    }

    const int raw = blockIdx.x;               // 2304 = 8 XCD * 288
    const int xcd = raw & 7;
    const int idx = raw >> 3;                 // 0..287
    const int bs  = xcd * 36 + (idx >> 3);    // b*144 + r, XCD-exclusive
    const int head = idx & 7;
    const int b   = bs / 144;
    const int r   = bs % 144;
    const int ni   = r / 6;                   // patch row 0..23
    const int nj0p = (r % 6) * 4;             // first patch col of strip
    const int c0   = head * 32;
    const float qscale = 0.17677669529663687f;

    // ---- stage + transform: 320 units = (chg 0..3, row 0..7, colpair 0..9) ----
    #pragma unroll
    for (int pass = 0; pass < 2; ++pass) {
        const int u = pass * 256 + t;
        if (u < 320) {
            const int chg = u / 80;
            const int rem = u % 80;
            const int row = rem / 10, cp = rem % 10;
            const int col0 = 2 * cp;
            const int rg = min(4 * ni + row, 95);
            const int cg = 16 * (r % 6) + col0;
            const int cb8 = c0 + 8 * chg;
            const float* xb = x + (((size_t)b * 256 + cb8) * 96 + rg) * 96;
            const f4 kw0 = *(const f4*)&qkv_w[256 + cb8], kw1 = *(const f4*)&qkv_w[260 + cb8];
            const f4 kb0 = *(const f4*)&qkv_b[256 + cb8], kb1 = *(const f4*)&qkv_b[260 + cb8];
            const f4 vw0 = *(const f4*)&qkv_w[512 + cb8], vw1 = *(const f4*)&qkv_w[516 + cb8];
            const f4 vb0 = *(const f4*)&qkv_b[512 + cb8], vb1 = *(const f4*)&qkv_b[516 + cb8];
            const f4 qw0 = *(const f4*)&qkv_w[cb8],       qw1 = *(const f4*)&qkv_w[cb8 + 4];
            const f4 qb0 = *(const f4*)&qkv_b[cb8],       qb1 = *(const f4*)&qkv_b[cb8 + 4];
            const bool own = (row < 4) && (col0 < 16);
            bf16x8 k0v, k1v, q0v, q1v;
            #pragma unroll
            for (int j = 0; j < 8; ++j) {
                const float kw = j < 4 ? kw0[j] : kw1[j - 4];
                const float kb = j < 4 ? kb0[j] : kb1[j - 4];
                const float vw = j < 4 ? vw0[j] : vw1[j - 4];
                const float vb = j < 4 ? vb0[j] : vb1[j - 4];
                const float qw = (j < 4 ? qw0[j] : qw1[j - 4]) * qscale;
                const float qb = (j < 4 ? qb0[j] : qb1[j - 4]) * qscale;
                f2 xv;
                if (cg <= 94) {
                    xv = *(const f2*)&xb[(size_t)j * 9216 + cg];
                } else {                      // cols 96..99 clamp to col 95
                    const float s = xb[(size_t)j * 9216 + 95];
                    xv.x = s; xv.y = s;
                }
                k0v[j] = (__bf16)(xv.x * kw + kb);
                k1v[j] = (__bf16)(xv.y * kw + kb);
                bf16x2 vv;
                vv[0] = (__bf16)(xv.x * vw + vb);
                vv[1] = (__bf16)(xv.y * vw + vb);
                *(bf16x2*)&Vreg[8 * chg + j][row * 24 + col0] = vv;
                q0v[j] = (__bf16)(xv.x * qw + qb);
                q1v[j] = (__bf16)(xv.y * qw + qb);
            }
            const int px0 = row * 20 + col0;
            *(bf16x8*)&Kreg[px0][8 * chg]     = k0v;
            *(bf16x8*)&Kreg[px0 + 1][8 * chg] = k1v;
            if (own) {
                const int wvp = col0 >> 2;
                const int q0 = (row << 2) | (col0 & 3);
                *(bf16x8*)&Qreg[wvp][q0][8 * chg]     = q0v;
                *(bf16x8*)&Qreg[wvp][q0 + 1][8 * chg] = q1v;
            }
        }
    }
    __syncthreads();

    const int wv = t >> 6, l = t & 63;
    const int l16 = l & 15, lg = l >> 4;
    const int nj = nj0p + wv;
    const int cw = 4 * wv;                   // patch origin col within region

    // ---- QK^T: S(16x64) via 4 x mfma, all-vector LDS operands ----
    const f32x4 zf = {0.f, 0.f, 0.f, 0.f};
    const bf16x8 qf = *(const bf16x8*)&Qreg[wv][l16][lg * 8];
    f32x4 sacc[4];
    #pragma unroll
    for (int t4 = 0; t4 < 4; ++t4) {
        const int px = l16 + 16 * t4;
        const bf16x8 kf =
            *(const bf16x8*)&Kreg[(px >> 3) * 20 + cw + (px & 7)][lg * 8];
        sacc[t4] = __builtin_amdgcn_mfma_f32_16x16x32_bf16(qf, kf, zf, 0, 0, 0);
    }

    // ---- bias + row softmax ----
    float sv[4][4], rinv[4];
    #pragma unroll
    for (int rr = 0; rr < 4; ++rr) {
        const int qrow = lg * 4 + rr;
        const int qi = qrow >> 2, qj = qrow & 3;
        float m = -1e30f;
        #pragma unroll
        for (int t4 = 0; t4 < 4; ++t4) {
            const int kcol = l16 + 16 * t4;
            const int ki = kcol >> 3, kj = kcol & 7;
            const float s = sacc[t4][rr]
                + pos_table[((qi - ki + 7) * 15 + (qj - kj + 7)) * 8 + head];
            sv[t4][rr] = s;
            m = fmaxf(m, s);
        }
        #pragma unroll
        for (int off = 8; off >= 1; off >>= 1)
            m = fmaxf(m, __shfl_xor(m, off, 16));
        float sum = 0.f;
        #pragma unroll
        for (int t4 = 0; t4 < 4; ++t4) {
            const float p = __expf(sv[t4][rr] - m);
            sv[t4][rr] = p;
            sum += p;
        }
        #pragma unroll
        for (int off = 8; off >= 1; off >>= 1)
            sum += __shfl_xor(sum, off, 16);
        rinv[rr] = 1.0f / sum;
        #pragma unroll
        for (int t4 = 0; t4 < 4; ++t4)
            Ps[wv][qrow][l16 + 16 * t4] = (__bf16)sv[t4][rr];
    }
    // Ps is wave-private: compiler's lgkmcnt ordering suffices, no barrier.

    // ---- PV: O(16x32) = P(16x64) * V(64x32), V via aligned b64 pairs ----
    f32x4 oa = zf, ob = zf;
    #pragma unroll
    for (int kt = 0; kt < 2; ++kt) {
        const bf16x8 pf = *(const bf16x8*)&Ps[wv][l16][lg * 8 + 32 * kt];
        const int pos = (4 * kt + lg) * 24 + cw;
        const bf16x4 a0 = *(const bf16x4*)&Vreg[l16][pos];
        const bf16x4 a1 = *(const bf16x4*)&Vreg[l16][pos + 4];
        const bf16x4 b0 = *(const bf16x4*)&Vreg[16 + l16][pos];
        const bf16x4 b1 = *(const bf16x4*)&Vreg[16 + l16][pos + 4];
        bf16x8 v0, v1;
        #pragma unroll
        for (int j = 0; j < 4; ++j) {
            v0[j] = a0[j]; v0[4 + j] = a1[j];
            v1[j] = b0[j]; v1[4 + j] = b1[j];
        }
        oa = __builtin_amdgcn_mfma_f32_16x16x32_bf16(pf, v0, oa, 0, 0, 0);
        ob = __builtin_amdgcn_mfma_f32_16x16x32_bf16(pf, v1, ob, 0, 0, 0);
    }

    // ---- epilogue: store O to fragment-linear mid ----
    const int pbase = ni * 384 + lg * 96 + nj * 4;
    __bf16* mbb = mid + (size_t)b * 9216 * 256;
    #pragma unroll
    for (int rr = 0; rr < 4; ++rr) {
        const int p = pbase + rr;
        __bf16* dst = mbb + ((p >> 4) * 8 + head) * 512 + (p & 15) * 32;
        dst[l16]      = (__bf16)(oa[rr] * rinv[rr]);
        dst[16 + l16] = (__bf16)(ob[rr] * rinv[rr]);
    }
}

// y[b,o,p] = sum_c w[o,c]*mid[b,p,c]; fragment-linear operands. (R17, frozen)
__global__ __launch_bounds__(256) void proj(
    const __bf16* __restrict__ wbf,   // fragment-linear [16][8][512]
    const __bf16* __restrict__ mid,   // fragment-linear per b [576][8][512]
    float* __restrict__ y)
{
    __shared__ __align__(16) __bf16 wlds[4][8][512];   // 32 KB

    const int t  = threadIdx.x;
    const int wv = t >> 6;
    const int l  = t & 63;
    const int l16 = l & 15, lg = l >> 4;
    const int fragoff = l16 * 32 + lg * 8;

    const int raw = blockIdx.x;               // 0..1151 = 8 XCD * 144
    const int xcd = raw & 7;
    const int seq = raw >> 3;                 // 0..143
    const int pair = seq >> 2;                // 0..35
    const int og4  = seq & 3;
    const int bs = xcd * 36 + pair;           // matches attn's bs on this XCD
    const int b  = bs / 144;
    const int r  = bs % 144;
    const int ni = r / 6, wcol = r % 6;
    const int ot0 = og4 * 4;
    const int pt  = (4 * ni + wv) * 6 + wcol; // wave's ptile

    // stage 32 KB w slab (4 KB per instruction, fully coalesced)
    {
        const bf16x8* wsrc = (const bf16x8*)&wbf[(size_t)ot0 * 8 * 512];
        bf16x8* wdst = (bf16x8*)&wlds[0][0][0];
        #pragma unroll
        for (int i = 0; i < 8; ++i)
            wdst[t + 256 * i] = wsrc[t + 256 * i];
    }
    __syncthreads();

    // ptile's 8 mid fragments -> registers (read once, XCD-local)
    const __bf16* midb = mid + ((size_t)b * 9216 + (size_t)pt * 16) * 256;
    bf16x8 bfr[8];
    #pragma unroll
    for (int kt = 0; kt < 8; ++kt)
        bfr[kt] = *(const bf16x8*)&midb[kt * 512 + fragoff];

    f32x4 acc[4];
    #pragma unroll
    for (int ot = 0; ot < 4; ++ot) acc[ot] = (f32x4){0.f, 0.f, 0.f, 0.f};

    #pragma unroll
    for (int ot = 0; ot < 4; ++ot)
        #pragma unroll
        for (int kt = 0; kt < 8; ++kt) {
            const bf16x8 af = *(const bf16x8*)&wlds[ot][kt][fragoff];
            acc[ot] = __builtin_amdgcn_mfma_f32_16x16x32_bf16(af, bfr[kt], acc[ot], 0, 0, 0);
        }

    const int p = pt * 16 + l16;
    #pragma unroll
    for (int ot = 0; ot < 4; ++ot) {
        const int o = (ot0 + ot) * 16 + lg * 4;
        float* yb = y + ((size_t)b * 256 + o) * 9216 + p;
        #pragma unroll
        for (int rr = 0; rr < 4; ++rr)
            yb[(size_t)rr * 9216] = acc[ot][rr];
    }
}

extern "C" void kernel_launch(void* const* d_in, const int* in_sizes, int n_in,
                              void* d_out, int out_size, void* d_ws, size_t ws_size,
                              hipStream_t stream) {
    const float* x         = (const float*)d_in[0];
    const float* qkv_w     = (const float*)d_in[1];
    const float* qkv_b     = (const float*)d_in[2];
    const float* out_w     = (const float*)d_in[3];
    const float* pos_table = (const float*)d_in[4];
    float* y    = (float*)d_out;
    __bf16* mid = (__bf16*)d_ws;                              // 9.4 MB
    __bf16* wbf = (__bf16*)((char*)d_ws + (12u << 20));       // 128 KB @ 12MB

    patch_attn<<<dim3(2304), dim3(256), 0, stream>>>(
        x, qkv_w, qkv_b, pos_table, out_w, mid, wbf);
    proj<<<dim3(1152), dim3(256), 0, stream>>>(
        wbf, mid, y);
}